// Round 1
// 224.804 us; speedup vs baseline: 1.0013x; 1.0013x over previous
//
#include <hip/hip_runtime.h>
#include <hip/hip_bf16.h>

#define B_ 8
#define N_ 4096
#define C_ 512
#define H_ 4
#define EPS_ 1e-4f
#define E60P 1.14200739e26f   // expf(60)
#define E60M 8.7565108e-27f   // expf(-60)

typedef __attribute__((ext_vector_type(8))) short short8;
typedef __attribute__((ext_vector_type(4))) float floatx4;
typedef __attribute__((ext_vector_type(2))) float floatx2;
typedef __attribute__((ext_vector_type(4))) unsigned short ushort4_t;
typedef unsigned short ushort_t;

__device__ __forceinline__ float sigmoidf_(float v) {
    return 1.0f / (1.0f + expf(-v));
}

// Fragment-packed layout for GEMM operands (Z and W):
//   chunk(tile t, half w, k0, ks, f) = 512 bf16 (1 KiB) in exact MFMA lane
//   order: element lane*8+kb holds Op[t*128+w*64+f*16+(lane&15)]
//                                   [k0*64+ks*32+(lane>>4)*8+kb]
__device__ __forceinline__ int pk_off(int t, int w, int k0, int ks, int f,
                                      int lane8, int kb) {
    return ((((t * 2 + w) * 16 + k0) * 2 + ks) * 4 + f) * 512 + lane8 * 8 + kb;
}

// async global->LDS, 16 B per lane (dest must be linear: base + lane*16)
__device__ __forceinline__ void gload16(const void* g, void* l) {
    __builtin_amdgcn_global_load_lds(
        (const __attribute__((address_space(1))) void*)g,
        (__attribute__((address_space(3))) void*)l, 16, 0, 0);
}

// ---------------------------------------------------------------------------
// K1: fused-direction per-subchunk partial sums, packed-f32 math, 8-deep
// load double-buffer. grid 1024 = chunk(4b)|ct(3b)|b(3b).
// ---------------------------------------------------------------------------
__global__ __launch_bounds__(256) void k_partials3(
    const float* __restrict__ x, const float* __restrict__ al,
    const float* __restrict__ dl, const float* __restrict__ bl,
    float* __restrict__ P)
{
    int bid   = blockIdx.x;
    int chunk = bid & 15;
    int ct    = (bid >> 4) & 7;
    int b     = bid >> 7;
    int lane  = threadIdx.x & 63;
    int wave  = threadIdx.x >> 6;
    int c     = ct * 64 + lane;
    int sub   = chunk * 4 + wave;     // fwd subchunk 0..63
    int t0f   = sub * 64;
    int t0b   = (63 - sub) * 64;      // bwd subchunk start (reversed time)

    float aa[4], dd[4], bb[4];
    { float4 v = ((const float4*)al)[c]; aa[0]=v.x; aa[1]=v.y; aa[2]=v.z; aa[3]=v.w; }
    { float4 v = ((const float4*)dl)[c]; dd[0]=v.x; dd[1]=v.y; dd[2]=v.z; dd[3]=v.w; }
    { float4 v = ((const float4*)bl)[c]; bb[0]=v.x; bb[1]=v.y; bb[2]=v.z; bb[3]=v.w; }

    float A[H_], ri[H_], Lh[H_];
    #pragma unroll
    for (int h = 0; h < H_; ++h) {
        float alpha = sigmoidf_(aa[h]);
        float delta = sigmoidf_(dd[h]);
        float beta  = sigmoidf_(bb[h]);
        A[h] = alpha * beta;
        float r = fminf(fmaxf(1.0f - alpha * delta, EPS_), 1.0f - EPS_);
        Lh[h] = logf(r);
        ri[h] = 1.0f / r;
    }
    const floatx2 E2P = {E60P, E60P};
    floatx2 A2[2]  = {{A[0],  A[1]},  {A[2],  A[3]}};
    floatx2 ri2[2] = {{ri[0], ri[1]}, {ri[2], ri[3]}};

    const float* xp = x + ((size_t)b * N_ + t0f) * C_ + c;

    // ---- forward pass
    floatx2 ep2[2], T2[2];
    #pragma unroll
    for (int p = 0; p < 2; ++p) {
        ep2[p] = (floatx2){expf(fminf(-Lh[2*p]   * (float)t0f, 60.0f)),
                           expf(fminf(-Lh[2*p+1] * (float)t0f, 60.0f))};
        T2[p]  = (floatx2){0.f, 0.f};
    }
    {
        float cur[8];
        #pragma unroll
        for (int j = 0; j < 8; ++j) cur[j] = xp[(size_t)j * C_];
        #pragma unroll 1
        for (int g = 0; g < 8; ++g) {
            float nxt[8];
            if (g < 7) {
                #pragma unroll
                for (int j = 0; j < 8; ++j)
                    nxt[j] = xp[(size_t)(g * 8 + 8 + j) * C_];
            }
            #pragma unroll
            for (int j = 0; j < 8; ++j) {
                floatx2 xv2 = {cur[j], cur[j]};
                #pragma unroll
                for (int p = 0; p < 2; ++p) {
                    T2[p] += (A2[p] * xv2) * ep2[p];
                    ep2[p] = __builtin_elementwise_min(ep2[p] * ri2[p], E2P);
                }
            }
            if (g < 7) {
                #pragma unroll
                for (int j = 0; j < 8; ++j) cur[j] = nxt[j];
            }
        }
        float* pp = P + ((size_t)b * 64 + sub) * (H_ * C_) + c;
        pp[0]      = T2[0].x;  pp[C_]     = T2[0].y;
        pp[2 * C_] = T2[1].x;  pp[3 * C_] = T2[1].y;
    }

    // ---- backward pass: t' = t0b + j, reads row 63-j (cache hit)
    #pragma unroll
    for (int p = 0; p < 2; ++p) {
        ep2[p] = (floatx2){expf(fminf(-Lh[2*p]   * (float)t0b, 60.0f)),
                           expf(fminf(-Lh[2*p+1] * (float)t0b, 60.0f))};
        T2[p]  = (floatx2){0.f, 0.f};
    }
    {
        float cur[8];
        #pragma unroll
        for (int j = 0; j < 8; ++j) cur[j] = xp[(size_t)(63 - j) * C_];
        #pragma unroll 1
        for (int g = 0; g < 8; ++g) {
            float nxt[8];
            if (g < 7) {
                #pragma unroll
                for (int j = 0; j < 8; ++j)
                    nxt[j] = xp[(size_t)(63 - (g * 8 + 8 + j)) * C_];
            }
            #pragma unroll
            for (int j = 0; j < 8; ++j) {
                floatx2 xv2 = {cur[j], cur[j]};
                #pragma unroll
                for (int p = 0; p < 2; ++p) {
                    T2[p] += (A2[p] * xv2) * ep2[p];
                    ep2[p] = __builtin_elementwise_min(ep2[p] * ri2[p], E2P);
                }
            }
            if (g < 7) {
                #pragma unroll
                for (int j = 0; j < 8; ++j) cur[j] = nxt[j];
            }
        }
        float* pp = P + ((size_t)(8 + b) * 64 + (63 - sub)) * (H_ * C_) + c;
        pp[0]      = T2[0].x;  pp[C_]     = T2[0].y;
        pp[2 * C_] = T2[1].x;  pp[3 * C_] = T2[1].y;
    }
}

// ---------------------------------------------------------------------------
// K2: exclusive scan over the 64 subchunks, per (dir,b,c,h).
// Register-resident: 64 independent loads in flight (was a serial
// load->store->add chain = 64 dependent HBM round-trips).
// ---------------------------------------------------------------------------
__global__ __launch_bounds__(256) void k_scan(float* __restrict__ P)
{
    int bid = blockIdx.x;
    int ct  = bid & 7;
    int b   = (bid >> 3) & 7;
    int dir = bid >> 6;
    int cl  = threadIdx.x & 63;
    int h   = threadIdx.x >> 6;
    int c   = ct * 64 + cl;

    float* base = P + ((size_t)(dir * 8 + b) * 64) * (H_ * C_) + h * C_ + c;

    float v[64];
    #pragma unroll
    for (int s = 0; s < 64; ++s) v[s] = base[s * (H_ * C_)];

    float run = 0.0f;
    #pragma unroll
    for (int s = 0; s < 64; ++s) { float t = v[s]; v[s] = run; run += t; }

    #pragma unroll
    for (int s = 0; s < 64; ++s) base[s * (H_ * C_)] = v[s];
}

// ---------------------------------------------------------------------------
// K3: fused-direction apply, packed-f32 math, 8-deep load double-buffer;
// writes z directly in fragment-packed bf16 order.
// ---------------------------------------------------------------------------
__global__ __launch_bounds__(256) void k_apply3(
    const float* __restrict__ x, const float* __restrict__ al,
    const float* __restrict__ dl, const float* __restrict__ bl,
    const float* __restrict__ eta, const float* __restrict__ P,
    ushort_t* __restrict__ Zp)
{
    int bid   = blockIdx.x;
    int chunk = bid & 15;
    int ct    = (bid >> 4) & 7;
    int b     = bid >> 7;
    int lane  = threadIdx.x & 63;
    int wave  = threadIdx.x >> 6;
    int c     = ct * 64 + lane;
    int sub   = chunk * 4 + wave;
    int t0f   = sub * 64;
    int t0b   = (63 - sub) * 64;

    int ksv = lane >> 5, qv = (lane >> 3) & 3, kbv = lane & 7;
    int mt  = b * 32 + (t0f >> 7);
    int wq  = (t0f >> 6) & 1;
    // incremental packed offsets: off = offc + (i>>4)*512 + (i&15)*8
    int offcF = pk_off(mt, wq, ct,     ksv, 0, qv * 16, kbv);
    int offcB = pk_off(mt, wq, 8 + ct, ksv, 0, qv * 16, kbv);

    float aa[4], dd[4], bb[4], ee[4];
    { float4 v = ((const float4*)al )[c]; aa[0]=v.x; aa[1]=v.y; aa[2]=v.z; aa[3]=v.w; }
    { float4 v = ((const float4*)dl )[c]; dd[0]=v.x; dd[1]=v.y; dd[2]=v.z; dd[3]=v.w; }
    { float4 v = ((const float4*)bl )[c]; bb[0]=v.x; bb[1]=v.y; bb[2]=v.z; bb[3]=v.w; }
    { float4 v = ((const float4*)eta)[c]; ee[0]=v.x; ee[1]=v.y; ee[2]=v.z; ee[3]=v.w; }

    float A[H_], rr[H_], ri[H_], Lh[H_];
    #pragma unroll
    for (int h = 0; h < H_; ++h) {
        float alpha = sigmoidf_(aa[h]);
        float delta = sigmoidf_(dd[h]);
        float beta  = sigmoidf_(bb[h]);
        A[h] = alpha * beta;
        float r = fminf(fmaxf(1.0f - alpha * delta, EPS_), 1.0f - EPS_);
        Lh[h] = logf(r);
        rr[h] = r;
        ri[h] = 1.0f / r;
    }
    const floatx2 E2P = {E60P, E60P};
    const floatx2 E2M = {E60M, E60M};
    floatx2 A2[2]  = {{A[0],  A[1]},  {A[2],  A[3]}};
    floatx2 ri2[2] = {{ri[0], ri[1]}, {ri[2], ri[3]}};
    floatx2 rr2[2] = {{rr[0], rr[1]}, {rr[2], rr[3]}};
    floatx2 ee2[2] = {{ee[0], ee[1]}, {ee[2], ee[3]}};

    const float* xp = x + ((size_t)b * N_ + t0f) * C_ + c;

    // ---- forward
    {
        const float* cp = P + ((size_t)b * 64 + sub) * (H_ * C_) + c;
        floatx2 ep2[2], em2[2], S2[2];
        #pragma unroll
        for (int p = 0; p < 2; ++p) {
            ep2[p] = (floatx2){expf(fminf(-Lh[2*p]   * (float)t0f, 60.0f)),
                               expf(fminf(-Lh[2*p+1] * (float)t0f, 60.0f))};
            em2[p] = (floatx2){expf(fmaxf( Lh[2*p]   * (float)t0f, -60.0f)),
                               expf(fmaxf( Lh[2*p+1] * (float)t0f, -60.0f))};
            S2[p]  = (floatx2){cp[(2*p) * C_], cp[(2*p+1) * C_]};
        }
        float cur[8];
        #pragma unroll
        for (int j = 0; j < 8; ++j) cur[j] = xp[(size_t)j * C_];
        #pragma unroll 1
        for (int g = 0; g < 8; ++g) {
            float nxt[8];
            if (g < 7) {
                #pragma unroll
                for (int j = 0; j < 8; ++j)
                    nxt[j] = xp[(size_t)(g * 8 + 8 + j) * C_];
            }
            #pragma unroll
            for (int j = 0; j < 8; ++j) {
                int i = g * 8 + j;
                floatx2 xv2 = {cur[j], cur[j]};
                floatx2 acc = {0.f, 0.f};
                #pragma unroll
                for (int p = 0; p < 2; ++p) {
                    S2[p] += (A2[p] * xv2) * ep2[p];
                    ep2[p] = __builtin_elementwise_min(ep2[p] * ri2[p], E2P);
                    acc   += ee2[p] * (em2[p] * S2[p]);
                    em2[p] = __builtin_elementwise_max(em2[p] * rr2[p], E2M);
                }
                float y = acc.x + acc.y;
                __hip_bfloat16 yb = __float2bfloat16(y);
                Zp[offcF + (i >> 4) * 512 + (i & 15) * 8] = *(ushort_t*)&yb;
            }
            if (g < 7) {
                #pragma unroll
                for (int j = 0; j < 8; ++j) cur[j] = nxt[j];
            }
        }
    }

    // ---- backward: t' = t0b + j ascending, output row i = 63 - j
    {
        const float* cp = P + ((size_t)(8 + b) * 64 + (63 - sub)) * (H_ * C_) + c;
        floatx2 ep2[2], em2[2], S2[2];
        #pragma unroll
        for (int p = 0; p < 2; ++p) {
            ep2[p] = (floatx2){expf(fminf(-Lh[2*p]   * (float)t0b, 60.0f)),
                               expf(fminf(-Lh[2*p+1] * (float)t0b, 60.0f))};
            em2[p] = (floatx2){expf(fmaxf( Lh[2*p]   * (float)t0b, -60.0f)),
                               expf(fmaxf( Lh[2*p+1] * (float)t0b, -60.0f))};
            S2[p]  = (floatx2){cp[(2*p) * C_], cp[(2*p+1) * C_]};
        }
        float cur[8];
        #pragma unroll
        for (int j = 0; j < 8; ++j) cur[j] = xp[(size_t)(63 - j) * C_];
        #pragma unroll 1
        for (int g = 0; g < 8; ++g) {
            float nxt[8];
            if (g < 7) {
                #pragma unroll
                for (int j = 0; j < 8; ++j)
                    nxt[j] = xp[(size_t)(63 - (g * 8 + 8 + j)) * C_];
            }
            #pragma unroll
            for (int j = 0; j < 8; ++j) {
                int i = 63 - (g * 8 + j);
                floatx2 xv2 = {cur[j], cur[j]};
                floatx2 acc = {0.f, 0.f};
                #pragma unroll
                for (int p = 0; p < 2; ++p) {
                    S2[p] += (A2[p] * xv2) * ep2[p];
                    ep2[p] = __builtin_elementwise_min(ep2[p] * ri2[p], E2P);
                    acc   += ee2[p] * (em2[p] * S2[p]);
                    em2[p] = __builtin_elementwise_max(em2[p] * rr2[p], E2M);
                }
                float y = acc.x + acc.y;
                __hip_bfloat16 yb = __float2bfloat16(y);
                Zp[offcB + (i >> 4) * 512 + (i & 15) * 8] = *(ushort_t*)&yb;
            }
            if (g < 7) {
                #pragma unroll
                for (int j = 0; j < 8; ++j) cur[j] = nxt[j];
            }
        }
    }
}

// ---------------------------------------------------------------------------
// cvt + permute proj_w fp32 -> fragment-packed bf16, 4 elems/thread
// (float4 load, ushort4 store: kb = kk&7 stays within one aligned quad)
// ---------------------------------------------------------------------------
__global__ __launch_bounds__(256) void k_cvtw2(const float* __restrict__ w,
                                               ushort_t* __restrict__ Wp)
{
    int i4 = blockIdx.x * 256 + threadIdx.x;   // 131072 total
    int i  = i4 << 2;
    int n = i >> 10, k = i & 1023;
    int nt = n >> 7, rn = n & 127;
    int k0 = k >> 6, kk = k & 63;
    int off = pk_off(nt, rn >> 6, k0, kk >> 5, (rn >> 4) & 3,
                     ((kk >> 3) & 3) * 16 + (rn & 15), kk & 7);
    float4 v = ((const float4*)w)[i4];
    ushort4_t r;
    { __hip_bfloat16 t = __float2bfloat16(v.x); r.x = *(ushort_t*)&t; }
    { __hip_bfloat16 t = __float2bfloat16(v.y); r.y = *(ushort_t*)&t; }
    { __hip_bfloat16 t = __float2bfloat16(v.z); r.z = *(ushort_t*)&t; }
    { __hip_bfloat16 t = __float2bfloat16(v.w); r.w = *(ushort_t*)&t; }
    *(ushort4_t*)&Wp[off] = r;
}

// ---------------------------------------------------------------------------
// K4: GEMM out[32768,512] = Z @ W^T + bias, operands fragment-packed.
// m97 structure: BK=64 slice staged to LDS via global_load_lds width=16
// (packed layout is already linear -> wave-uniform dest constraint holds),
// 2-barrier single-buffer loop, per-ks fragment loads to keep live VGPRs
// low enough for 4 blocks/CU (16 waves -> cross-block latency hiding).
// XCD swizzle: bid&7 = XCD = mt&7.
// ---------------------------------------------------------------------------
__global__ __launch_bounds__(256, 4) void k_gemm3(
    const ushort_t* __restrict__ Zp, const ushort_t* __restrict__ Wp,
    const float* __restrict__ bias, float* __restrict__ out)
{
    // staging: A 16 KB + B 16 KB; reused as epilogue stg (16896 B)
    __shared__ __align__(16) char lds[32768];
    char*  ldsA = lds;            // [w][ks*4+f][512 bf16] linear
    char*  ldsB = lds + 16384;
    float* stg  = (float*)lds;

    int tid  = threadIdx.x;
    int lane = tid & 63, wave = tid >> 6;
    int wm   = wave & 1, wn = wave >> 1;
    int fr   = lane & 15, quad = lane >> 4;

    int bid = blockIdx.x;
    int mt  = ((bid >> 5) << 3) | (bid & 7);   // mt & 7 == bid & 7 == XCD
    int nt  = (bid >> 3) & 3;
    int m0  = mt * 128, n0 = nt * 128;

    const ushort_t* Az = Zp + ((size_t)(mt * 2) * 16) * 4096;  // w-half stride 65536
    const ushort_t* Bz = Wp + ((size_t)(nt * 2) * 16) * 4096;

    floatx4 acc[4][4];
    #pragma unroll
    for (int mf = 0; mf < 4; ++mf)
        #pragma unroll
        for (int nf = 0; nf < 4; ++nf)
            acc[mf][nf] = (floatx4){0.f, 0.f, 0.f, 0.f};

    for (int k0 = 0; k0 < 16; ++k0) {
        const ushort_t* As = Az + (size_t)k0 * 4096;
        const ushort_t* Bs = Bz + (size_t)k0 * 4096;
        // stage 32 KB: 8 x global_load_lds_dwordx4 per thread
        #pragma unroll
        for (int w = 0; w < 2; ++w)
            #pragma unroll
            for (int inst = 0; inst < 2; ++inst) {
                gload16(As + w * 65536 + inst * 2048 + tid * 8,
                        ldsA + w * 8192 + inst * 4096 + tid * 16);
                gload16(Bs + w * 65536 + inst * 2048 + tid * 8,
                        ldsB + w * 8192 + inst * 4096 + tid * 16);
            }
        asm volatile("s_waitcnt vmcnt(0)" ::: "memory");
        __syncthreads();

        #pragma unroll
        for (int ks = 0; ks < 2; ++ks) {
            short8 af[4], bf[4];
            #pragma unroll
            for (int f = 0; f < 4; ++f) {
                af[f] = *(const short8*)(ldsA + wm * 8192 + (ks * 4 + f) * 1024 + lane * 16);
                bf[f] = *(const short8*)(ldsB + wn * 8192 + (ks * 4 + f) * 1024 + lane * 16);
            }
            #pragma unroll
            for (int mf = 0; mf < 4; ++mf)
                #pragma unroll
                for (int nf = 0; nf < 4; ++nf)
                    acc[mf][nf] = __builtin_amdgcn_mfma_f32_16x16x32_bf16(
                        af[mf], bf[nf], acc[mf][nf], 0, 0, 0);
        }
        __syncthreads();
    }

    // ---- LDS-staged epilogue: 4 chunks of 32 rows, coalesced 512 B rows
    // (reuses staging LDS; k-loop's trailing barrier makes this safe)
    int rrow = tid >> 3;                 // 0..31
    int seg  = tid & 7;                  // 0..7
    int gcol = n0 + seg * 16;

    #pragma unroll
    for (int ch = 0; ch < 4; ++ch) {
        if ((wave & 1) == (ch >> 1)) {
            int ml = (ch & 1) * 2;
            #pragma unroll
            for (int mi = 0; mi < 2; ++mi) {
                #pragma unroll
                for (int nf = 0; nf < 4; ++nf) {
                    int col = wn * 64 + nf * 16 + fr;
                    #pragma unroll
                    for (int rg = 0; rg < 4; ++rg) {
                        int row = mi * 16 + quad * 4 + rg;
                        stg[row * 132 + col] = acc[ml + mi][nf][rg];
                    }
                }
            }
        }
        __syncthreads();
        {
            int gm = m0 + ch * 32 + rrow;
            const float* s = &stg[rrow * 132 + seg * 16];
            #pragma unroll
            for (int k = 0; k < 4; ++k) {
                float4 v  = *(const float4*)&s[k * 4];
                float4 bv = *(const float4*)&bias[gcol + k * 4];
                v.x += bv.x; v.y += bv.y; v.z += bv.z; v.w += bv.w;
                *(float4*)&out[(size_t)gm * 512 + gcol + k * 4] = v;
            }
        }
        __syncthreads();
    }
}

// ---------------------------------------------------------------------------
extern "C" void kernel_launch(void* const* d_in, const int* in_sizes, int n_in,
                              void* d_out, int out_size, void* d_ws, size_t ws_size,
                              hipStream_t stream)
{
    const float* x  = (const float*)d_in[0];
    const float* al = (const float*)d_in[1];
    const float* dl = (const float*)d_in[2];
    const float* bl = (const float*)d_in[3];
    const float* et = (const float*)d_in[4];
    const float* pw = (const float*)d_in[5];
    const float* pb = (const float*)d_in[6];
    float* out = (float*)d_out;

    // workspace:
    //   Zp bf16 packed [32768,1024] : 67,108,864 B
    //   P  f32  [2,B,64,H,C]        :  8,388,608 B
    //   Wp bf16 packed [512,1024]   :  1,048,576 B
    ushort_t* Zp = (ushort_t*)d_ws;
    float*    P  = (float*)((char*)d_ws + 67108864);
    ushort_t* Wp = (ushort_t*)((char*)d_ws + 75497472);

    hipLaunchKernelGGL(k_cvtw2,     dim3(512),  dim3(256), 0, stream, pw, Wp);
    hipLaunchKernelGGL(k_partials3, dim3(1024), dim3(256), 0, stream, x, al, dl, bl, P);
    hipLaunchKernelGGL(k_scan,      dim3(128),  dim3(256), 0, stream, P);
    hipLaunchKernelGGL(k_apply3,    dim3(1024), dim3(256), 0, stream, x, al, dl, bl, et, P, Zp);
    hipLaunchKernelGGL(k_gemm3,     dim3(1024), dim3(256), 0, stream, Zp, Wp, pb, out);
}

// Round 2
// 221.443 us; speedup vs baseline: 1.0165x; 1.0152x over previous
//
#include <hip/hip_runtime.h>
#include <hip/hip_bf16.h>

#define B_ 8
#define N_ 4096
#define C_ 512
#define H_ 4
#define EPS_ 1e-4f
#define E60P 1.14200739e26f   // expf(60)
#define E60M 8.7565108e-27f   // expf(-60)

typedef __attribute__((ext_vector_type(8))) short short8;
typedef __attribute__((ext_vector_type(4))) float floatx4;
typedef __attribute__((ext_vector_type(2))) float floatx2;
typedef __attribute__((ext_vector_type(4))) unsigned short ushort4_t;
typedef unsigned short ushort_t;

__device__ __forceinline__ float sigmoidf_(float v) {
    return 1.0f / (1.0f + expf(-v));
}

// Fragment-packed layout for GEMM operands (Z and W):
//   chunk(tile t, half w, k0, ks, f) = 512 bf16 (1 KiB) in exact MFMA lane
//   order: element lane*8+kb holds Op[t*128+w*64+f*16+(lane&15)]
//                                   [k0*64+ks*32+(lane>>4)*8+kb]
__device__ __forceinline__ int pk_off(int t, int w, int k0, int ks, int f,
                                      int lane8, int kb) {
    return ((((t * 2 + w) * 16 + k0) * 2 + ks) * 4 + f) * 512 + lane8 * 8 + kb;
}

// async global->LDS, 16 B per lane (dest must be linear: base + lane*16)
__device__ __forceinline__ void gload16(const void* g, void* l) {
    __builtin_amdgcn_global_load_lds(
        (const __attribute__((address_space(1))) void*)g,
        (__attribute__((address_space(3))) void*)l, 16, 0, 0);
}

// ---------------------------------------------------------------------------
// K1: fused-direction per-subchunk partial sums. Folded state Ae = A*ep
// (saves one pk_mul per pair per step); 16-deep x prefetch.
// grid 1024 = chunk(4b)|ct(3b)|b(3b).
// ---------------------------------------------------------------------------
__global__ __launch_bounds__(256) void k_partials4(
    const float* __restrict__ x, const float* __restrict__ al,
    const float* __restrict__ dl, const float* __restrict__ bl,
    float* __restrict__ P)
{
    int bid   = blockIdx.x;
    int chunk = bid & 15;
    int ct    = (bid >> 4) & 7;
    int b     = bid >> 7;
    int lane  = threadIdx.x & 63;
    int wave  = threadIdx.x >> 6;
    int c     = ct * 64 + lane;
    int sub   = chunk * 4 + wave;     // fwd subchunk 0..63
    int t0f   = sub * 64;
    int t0b   = (63 - sub) * 64;      // bwd subchunk start (reversed time)

    float aa[4], dd[4], bb[4];
    { float4 v = ((const float4*)al)[c]; aa[0]=v.x; aa[1]=v.y; aa[2]=v.z; aa[3]=v.w; }
    { float4 v = ((const float4*)dl)[c]; dd[0]=v.x; dd[1]=v.y; dd[2]=v.z; dd[3]=v.w; }
    { float4 v = ((const float4*)bl)[c]; bb[0]=v.x; bb[1]=v.y; bb[2]=v.z; bb[3]=v.w; }

    float A[H_], ri[H_], Lh[H_];
    #pragma unroll
    for (int h = 0; h < H_; ++h) {
        float alpha = sigmoidf_(aa[h]);
        float delta = sigmoidf_(dd[h]);
        float beta  = sigmoidf_(bb[h]);
        A[h] = alpha * beta;
        float r = fminf(fmaxf(1.0f - alpha * delta, EPS_), 1.0f - EPS_);
        Lh[h] = logf(r);
        ri[h] = 1.0f / r;
    }
    floatx2 ri2[2]  = {{ri[0], ri[1]}, {ri[2], ri[3]}};
    floatx2 AEP2[2] = {{A[0] * E60P, A[1] * E60P}, {A[2] * E60P, A[3] * E60P}};

    const float* xp = x + ((size_t)b * N_ + t0f) * C_ + c;

    // ---- forward pass
    floatx2 Ae2[2], T2[2];
    #pragma unroll
    for (int p = 0; p < 2; ++p) {
        Ae2[p] = (floatx2){A[2*p]   * expf(fminf(-Lh[2*p]   * (float)t0f, 60.0f)),
                           A[2*p+1] * expf(fminf(-Lh[2*p+1] * (float)t0f, 60.0f))};
        T2[p]  = (floatx2){0.f, 0.f};
    }
    {
        float cur[16];
        #pragma unroll
        for (int j = 0; j < 16; ++j) cur[j] = xp[(size_t)j * C_];
        #pragma unroll 1
        for (int g = 0; g < 4; ++g) {
            float nxt[16];
            if (g < 3) {
                #pragma unroll
                for (int j = 0; j < 16; ++j)
                    nxt[j] = xp[(size_t)(g * 16 + 16 + j) * C_];
            }
            #pragma unroll
            for (int j = 0; j < 16; ++j) {
                floatx2 xv2 = {cur[j], cur[j]};
                #pragma unroll
                for (int p = 0; p < 2; ++p) {
                    T2[p] += Ae2[p] * xv2;
                    Ae2[p] = __builtin_elementwise_min(Ae2[p] * ri2[p], AEP2[p]);
                }
            }
            if (g < 3) {
                #pragma unroll
                for (int j = 0; j < 16; ++j) cur[j] = nxt[j];
            }
        }
        float* pp = P + ((size_t)b * 64 + sub) * (H_ * C_) + c;
        pp[0]      = T2[0].x;  pp[C_]     = T2[0].y;
        pp[2 * C_] = T2[1].x;  pp[3 * C_] = T2[1].y;
    }

    // ---- backward pass: reads same 64 rows in reverse (cache hit)
    #pragma unroll
    for (int p = 0; p < 2; ++p) {
        Ae2[p] = (floatx2){A[2*p]   * expf(fminf(-Lh[2*p]   * (float)t0b, 60.0f)),
                           A[2*p+1] * expf(fminf(-Lh[2*p+1] * (float)t0b, 60.0f))};
        T2[p]  = (floatx2){0.f, 0.f};
    }
    {
        float cur[16];
        #pragma unroll
        for (int j = 0; j < 16; ++j) cur[j] = xp[(size_t)(63 - j) * C_];
        #pragma unroll 1
        for (int g = 0; g < 4; ++g) {
            float nxt[16];
            if (g < 3) {
                #pragma unroll
                for (int j = 0; j < 16; ++j)
                    nxt[j] = xp[(size_t)(63 - (g * 16 + 16 + j)) * C_];
            }
            #pragma unroll
            for (int j = 0; j < 16; ++j) {
                floatx2 xv2 = {cur[j], cur[j]};
                #pragma unroll
                for (int p = 0; p < 2; ++p) {
                    T2[p] += Ae2[p] * xv2;
                    Ae2[p] = __builtin_elementwise_min(Ae2[p] * ri2[p], AEP2[p]);
                }
            }
            if (g < 3) {
                #pragma unroll
                for (int j = 0; j < 16; ++j) cur[j] = nxt[j];
            }
        }
        float* pp = P + ((size_t)(8 + b) * 64 + (63 - sub)) * (H_ * C_) + c;
        pp[0]      = T2[0].x;  pp[C_]     = T2[0].y;
        pp[2 * C_] = T2[1].x;  pp[3 * C_] = T2[1].y;
    }
}

// ---------------------------------------------------------------------------
// K2: exclusive scan over the 64 subchunks, per (dir,b,c,h).
// Register-resident: 64 independent loads in flight.
// ---------------------------------------------------------------------------
__global__ __launch_bounds__(256) void k_scan(float* __restrict__ P)
{
    int bid = blockIdx.x;
    int ct  = bid & 7;
    int b   = (bid >> 3) & 7;
    int dir = bid >> 6;
    int cl  = threadIdx.x & 63;
    int h   = threadIdx.x >> 6;
    int c   = ct * 64 + cl;

    float* base = P + ((size_t)(dir * 8 + b) * 64) * (H_ * C_) + h * C_ + c;

    float v[64];
    #pragma unroll
    for (int s = 0; s < 64; ++s) v[s] = base[s * (H_ * C_)];

    float run = 0.0f;
    #pragma unroll
    for (int s = 0; s < 64; ++s) { float t = v[s]; v[s] = run; run += t; }

    #pragma unroll
    for (int s = 0; s < 64; ++s) base[s * (H_ * C_)] = v[s];
}

// ---------------------------------------------------------------------------
// K3: fused-direction apply. Folded Ae = A*ep state (7 pk-ops/pair/step,
// was 9); 16-deep x prefetch; writes z in fragment-packed bf16 order.
// ---------------------------------------------------------------------------
__global__ __launch_bounds__(256) void k_apply4(
    const float* __restrict__ x, const float* __restrict__ al,
    const float* __restrict__ dl, const float* __restrict__ bl,
    const float* __restrict__ eta, const float* __restrict__ P,
    ushort_t* __restrict__ Zp)
{
    int bid   = blockIdx.x;
    int chunk = bid & 15;
    int ct    = (bid >> 4) & 7;
    int b     = bid >> 7;
    int lane  = threadIdx.x & 63;
    int wave  = threadIdx.x >> 6;
    int c     = ct * 64 + lane;
    int sub   = chunk * 4 + wave;
    int t0f   = sub * 64;
    int t0b   = (63 - sub) * 64;

    int ksv = lane >> 5, qv = (lane >> 3) & 3, kbv = lane & 7;
    int mt  = b * 32 + (t0f >> 7);
    int wq  = (t0f >> 6) & 1;
    // incremental packed offsets: off = offc + (i>>4)*512 + (i&15)*8
    int offcF = pk_off(mt, wq, ct,     ksv, 0, qv * 16, kbv);
    int offcB = pk_off(mt, wq, 8 + ct, ksv, 0, qv * 16, kbv);

    float aa[4], dd[4], bb[4], ee[4];
    { float4 v = ((const float4*)al )[c]; aa[0]=v.x; aa[1]=v.y; aa[2]=v.z; aa[3]=v.w; }
    { float4 v = ((const float4*)dl )[c]; dd[0]=v.x; dd[1]=v.y; dd[2]=v.z; dd[3]=v.w; }
    { float4 v = ((const float4*)bl )[c]; bb[0]=v.x; bb[1]=v.y; bb[2]=v.z; bb[3]=v.w; }
    { float4 v = ((const float4*)eta)[c]; ee[0]=v.x; ee[1]=v.y; ee[2]=v.z; ee[3]=v.w; }

    float A[H_], rr[H_], ri[H_], Lh[H_];
    #pragma unroll
    for (int h = 0; h < H_; ++h) {
        float alpha = sigmoidf_(aa[h]);
        float delta = sigmoidf_(dd[h]);
        float beta  = sigmoidf_(bb[h]);
        A[h] = alpha * beta;
        float r = fminf(fmaxf(1.0f - alpha * delta, EPS_), 1.0f - EPS_);
        Lh[h] = logf(r);
        rr[h] = r;
        ri[h] = 1.0f / r;
    }
    const floatx2 E2M = {E60M, E60M};
    floatx2 ri2[2]  = {{ri[0], ri[1]}, {ri[2], ri[3]}};
    floatx2 rr2[2]  = {{rr[0], rr[1]}, {rr[2], rr[3]}};
    floatx2 ee2[2]  = {{ee[0], ee[1]}, {ee[2], ee[3]}};
    floatx2 AEP2[2] = {{A[0] * E60P, A[1] * E60P}, {A[2] * E60P, A[3] * E60P}};

    const float* xp = x + ((size_t)b * N_ + t0f) * C_ + c;

    // ---- forward
    {
        const float* cp = P + ((size_t)b * 64 + sub) * (H_ * C_) + c;
        floatx2 Ae2[2], em2[2], S2[2];
        #pragma unroll
        for (int p = 0; p < 2; ++p) {
            Ae2[p] = (floatx2){A[2*p]   * expf(fminf(-Lh[2*p]   * (float)t0f, 60.0f)),
                               A[2*p+1] * expf(fminf(-Lh[2*p+1] * (float)t0f, 60.0f))};
            em2[p] = (floatx2){expf(fmaxf( Lh[2*p]   * (float)t0f, -60.0f)),
                               expf(fmaxf( Lh[2*p+1] * (float)t0f, -60.0f))};
            S2[p]  = (floatx2){cp[(2*p) * C_], cp[(2*p+1) * C_]};
        }
        float cur[16];
        #pragma unroll
        for (int j = 0; j < 16; ++j) cur[j] = xp[(size_t)j * C_];
        #pragma unroll 1
        for (int g = 0; g < 4; ++g) {
            float nxt[16];
            if (g < 3) {
                #pragma unroll
                for (int j = 0; j < 16; ++j)
                    nxt[j] = xp[(size_t)(g * 16 + 16 + j) * C_];
            }
            #pragma unroll
            for (int j = 0; j < 16; ++j) {
                int i = g * 16 + j;
                floatx2 xv2 = {cur[j], cur[j]};
                floatx2 acc = {0.f, 0.f};
                #pragma unroll
                for (int p = 0; p < 2; ++p) {
                    S2[p] += Ae2[p] * xv2;
                    Ae2[p] = __builtin_elementwise_min(Ae2[p] * ri2[p], AEP2[p]);
                    acc   += ee2[p] * (em2[p] * S2[p]);
                    em2[p] = __builtin_elementwise_max(em2[p] * rr2[p], E2M);
                }
                float y = acc.x + acc.y;
                __hip_bfloat16 yb = __float2bfloat16(y);
                Zp[offcF + (i >> 4) * 512 + (i & 15) * 8] = *(ushort_t*)&yb;
            }
            if (g < 3) {
                #pragma unroll
                for (int j = 0; j < 16; ++j) cur[j] = nxt[j];
            }
        }
    }

    // ---- backward: t' = t0b + j ascending, output row i = 63 - j
    {
        const float* cp = P + ((size_t)(8 + b) * 64 + (63 - sub)) * (H_ * C_) + c;
        floatx2 Ae2[2], em2[2], S2[2];
        #pragma unroll
        for (int p = 0; p < 2; ++p) {
            Ae2[p] = (floatx2){A[2*p]   * expf(fminf(-Lh[2*p]   * (float)t0b, 60.0f)),
                               A[2*p+1] * expf(fminf(-Lh[2*p+1] * (float)t0b, 60.0f))};
            em2[p] = (floatx2){expf(fmaxf( Lh[2*p]   * (float)t0b, -60.0f)),
                               expf(fmaxf( Lh[2*p+1] * (float)t0b, -60.0f))};
            S2[p]  = (floatx2){cp[(2*p) * C_], cp[(2*p+1) * C_]};
        }
        float cur[16];
        #pragma unroll
        for (int j = 0; j < 16; ++j) cur[j] = xp[(size_t)(63 - j) * C_];
        #pragma unroll 1
        for (int g = 0; g < 4; ++g) {
            float nxt[16];
            if (g < 3) {
                #pragma unroll
                for (int j = 0; j < 16; ++j)
                    nxt[j] = xp[(size_t)(63 - (g * 16 + 16 + j)) * C_];
            }
            #pragma unroll
            for (int j = 0; j < 16; ++j) {
                int i = 63 - (g * 16 + j);
                floatx2 xv2 = {cur[j], cur[j]};
                floatx2 acc = {0.f, 0.f};
                #pragma unroll
                for (int p = 0; p < 2; ++p) {
                    S2[p] += Ae2[p] * xv2;
                    Ae2[p] = __builtin_elementwise_min(Ae2[p] * ri2[p], AEP2[p]);
                    acc   += ee2[p] * (em2[p] * S2[p]);
                    em2[p] = __builtin_elementwise_max(em2[p] * rr2[p], E2M);
                }
                float y = acc.x + acc.y;
                __hip_bfloat16 yb = __float2bfloat16(y);
                Zp[offcB + (i >> 4) * 512 + (i & 15) * 8] = *(ushort_t*)&yb;
            }
            if (g < 3) {
                #pragma unroll
                for (int j = 0; j < 16; ++j) cur[j] = nxt[j];
            }
        }
    }
}

// ---------------------------------------------------------------------------
// cvt + permute proj_w fp32 -> fragment-packed bf16, 4 elems/thread
// ---------------------------------------------------------------------------
__global__ __launch_bounds__(256) void k_cvtw2(const float* __restrict__ w,
                                               ushort_t* __restrict__ Wp)
{
    int i4 = blockIdx.x * 256 + threadIdx.x;   // 131072 total
    int i  = i4 << 2;
    int n = i >> 10, k = i & 1023;
    int nt = n >> 7, rn = n & 127;
    int k0 = k >> 6, kk = k & 63;
    int off = pk_off(nt, rn >> 6, k0, kk >> 5, (rn >> 4) & 3,
                     ((kk >> 3) & 3) * 16 + (rn & 15), kk & 7);
    float4 v = ((const float4*)w)[i4];
    ushort4_t r;
    { __hip_bfloat16 t = __float2bfloat16(v.x); r.x = *(ushort_t*)&t; }
    { __hip_bfloat16 t = __float2bfloat16(v.y); r.y = *(ushort_t*)&t; }
    { __hip_bfloat16 t = __float2bfloat16(v.z); r.z = *(ushort_t*)&t; }
    { __hip_bfloat16 t = __float2bfloat16(v.w); r.w = *(ushort_t*)&t; }
    *(ushort4_t*)&Wp[off] = r;
}

// ---------------------------------------------------------------------------
// K4: GEMM out[32768,512] = Z @ W^T + bias, operands fragment-packed.
// 2-phase prefetch: frags(k0) pulled to registers, barrier frees LDS, issue
// STAGE(k0+1) async, MFMA(k0) overlaps the loads, then vmcnt(0)+barrier+
// ds_read(k0+1). sched_barrier(0) pins the MFMA cluster between STAGE issue
// and the vmcnt wait. Single 32 KB buffer; ~3 blocks/CU.
// XCD swizzle: bid&7 = XCD = mt&7.
// ---------------------------------------------------------------------------
__global__ __launch_bounds__(256, 3) void k_gemm4(
    const ushort_t* __restrict__ Zp, const ushort_t* __restrict__ Wp,
    const float* __restrict__ bias, float* __restrict__ out)
{
    __shared__ __align__(16) char lds[32768];
    char*  ldsA = lds;            // [w][ks*4+f][512 bf16] linear
    char*  ldsB = lds + 16384;
    float* stg  = (float*)lds;

    int tid  = threadIdx.x;
    int lane = tid & 63, wave = tid >> 6;
    int wm   = wave & 1, wn = wave >> 1;
    int fr   = lane & 15, quad = lane >> 4;

    int bid = blockIdx.x;
    int mt  = ((bid >> 5) << 3) | (bid & 7);   // mt & 7 == bid & 7 == XCD
    int nt  = (bid >> 3) & 3;
    int m0  = mt * 128, n0 = nt * 128;

    const ushort_t* Az = Zp + ((size_t)(mt * 2) * 16) * 4096;  // w-half stride 65536
    const ushort_t* Bz = Wp + ((size_t)(nt * 2) * 16) * 4096;

    floatx4 acc[4][4];
    #pragma unroll
    for (int mf = 0; mf < 4; ++mf)
        #pragma unroll
        for (int nf = 0; nf < 4; ++nf)
            acc[mf][nf] = (floatx4){0.f, 0.f, 0.f, 0.f};

    // ---- prologue: stage k0=0, pull fragments to registers
    #pragma unroll
    for (int w = 0; w < 2; ++w)
        #pragma unroll
        for (int inst = 0; inst < 2; ++inst) {
            gload16(Az + w * 65536 + inst * 2048 + tid * 8,
                    ldsA + w * 8192 + inst * 4096 + tid * 16);
            gload16(Bz + w * 65536 + inst * 2048 + tid * 8,
                    ldsB + w * 8192 + inst * 4096 + tid * 16);
        }
    asm volatile("s_waitcnt vmcnt(0)" ::: "memory");
    __syncthreads();

    short8 af[2][4], bf[2][4];
    #pragma unroll
    for (int ks = 0; ks < 2; ++ks)
        #pragma unroll
        for (int f = 0; f < 4; ++f) {
            af[ks][f] = *(const short8*)(ldsA + wm * 8192 + (ks * 4 + f) * 1024 + lane * 16);
            bf[ks][f] = *(const short8*)(ldsB + wn * 8192 + (ks * 4 + f) * 1024 + lane * 16);
        }

    for (int k0 = 0; k0 < 16; ++k0) {
        __syncthreads();   // all waves' ds_reads of k0 done -> LDS reusable
        if (k0 < 15) {
            const ushort_t* As = Az + (size_t)(k0 + 1) * 4096;
            const ushort_t* Bs = Bz + (size_t)(k0 + 1) * 4096;
            #pragma unroll
            for (int w = 0; w < 2; ++w)
                #pragma unroll
                for (int inst = 0; inst < 2; ++inst) {
                    gload16(As + w * 65536 + inst * 2048 + tid * 8,
                            ldsA + w * 8192 + inst * 4096 + tid * 16);
                    gload16(Bs + w * 65536 + inst * 2048 + tid * 8,
                            ldsB + w * 8192 + inst * 4096 + tid * 16);
                }
        }
        __builtin_amdgcn_sched_barrier(0);   // loads issued before MFMAs
        #pragma unroll
        for (int ks = 0; ks < 2; ++ks)
            #pragma unroll
            for (int mf = 0; mf < 4; ++mf)
                #pragma unroll
                for (int nf = 0; nf < 4; ++nf)
                    acc[mf][nf] = __builtin_amdgcn_mfma_f32_16x16x32_bf16(
                        af[ks][mf], bf[ks][nf], acc[mf][nf], 0, 0, 0);
        __builtin_amdgcn_sched_barrier(0);   // MFMAs complete issue before wait
        if (k0 < 15) {
            asm volatile("s_waitcnt vmcnt(0)" ::: "memory");
            __syncthreads();
            #pragma unroll
            for (int ks = 0; ks < 2; ++ks)
                #pragma unroll
                for (int f = 0; f < 4; ++f) {
                    af[ks][f] = *(const short8*)(ldsA + wm * 8192 + (ks * 4 + f) * 1024 + lane * 16);
                    bf[ks][f] = *(const short8*)(ldsB + wn * 8192 + (ks * 4 + f) * 1024 + lane * 16);
                }
        }
    }
    __syncthreads();

    // ---- LDS-staged epilogue: 4 chunks of 32 rows, coalesced 512 B rows
    int rrow = tid >> 3;                 // 0..31
    int seg  = tid & 7;                  // 0..7
    int gcol = n0 + seg * 16;

    #pragma unroll
    for (int ch = 0; ch < 4; ++ch) {
        if ((wave & 1) == (ch >> 1)) {
            int ml = (ch & 1) * 2;
            #pragma unroll
            for (int mi = 0; mi < 2; ++mi) {
                #pragma unroll
                for (int nf = 0; nf < 4; ++nf) {
                    int col = wn * 64 + nf * 16 + fr;
                    #pragma unroll
                    for (int rg = 0; rg < 4; ++rg) {
                        int row = mi * 16 + quad * 4 + rg;
                        stg[row * 132 + col] = acc[ml + mi][nf][rg];
                    }
                }
            }
        }
        __syncthreads();
        {
            int gm = m0 + ch * 32 + rrow;
            const float* s = &stg[rrow * 132 + seg * 16];
            #pragma unroll
            for (int k = 0; k < 4; ++k) {
                float4 v  = *(const float4*)&s[k * 4];
                float4 bv = *(const float4*)&bias[gcol + k * 4];
                v.x += bv.x; v.y += bv.y; v.z += bv.z; v.w += bv.w;
                *(float4*)&out[(size_t)gm * 512 + gcol + k * 4] = v;
            }
        }
        __syncthreads();
    }
}

// ---------------------------------------------------------------------------
extern "C" void kernel_launch(void* const* d_in, const int* in_sizes, int n_in,
                              void* d_out, int out_size, void* d_ws, size_t ws_size,
                              hipStream_t stream)
{
    const float* x  = (const float*)d_in[0];
    const float* al = (const float*)d_in[1];
    const float* dl = (const float*)d_in[2];
    const float* bl = (const float*)d_in[3];
    const float* et = (const float*)d_in[4];
    const float* pw = (const float*)d_in[5];
    const float* pb = (const float*)d_in[6];
    float* out = (float*)d_out;

    // workspace:
    //   Zp bf16 packed [32768,1024] : 67,108,864 B
    //   P  f32  [2,B,64,H,C]        :  8,388,608 B
    //   Wp bf16 packed [512,1024]   :  1,048,576 B
    ushort_t* Zp = (ushort_t*)d_ws;
    float*    P  = (float*)((char*)d_ws + 67108864);
    ushort_t* Wp = (ushort_t*)((char*)d_ws + 75497472);

    hipLaunchKernelGGL(k_cvtw2,     dim3(512),  dim3(256), 0, stream, pw, Wp);
    hipLaunchKernelGGL(k_partials4, dim3(1024), dim3(256), 0, stream, x, al, dl, bl, P);
    hipLaunchKernelGGL(k_scan,      dim3(128),  dim3(256), 0, stream, P);
    hipLaunchKernelGGL(k_apply4,    dim3(1024), dim3(256), 0, stream, x, al, dl, bl, et, P, Zp);
    hipLaunchKernelGGL(k_gemm4,     dim3(1024), dim3(256), 0, stream, Zp, Wp, pb, out);
}

// Round 4
// 220.562 us; speedup vs baseline: 1.0206x; 1.0040x over previous
//
#include <hip/hip_runtime.h>
#include <hip/hip_bf16.h>

#define B_ 8
#define N_ 4096
#define C_ 512
#define H_ 4
#define EPS_ 1e-4f
#define E60P 1.14200739e26f   // expf(60)
#define E60M 8.7565108e-27f   // expf(-60)

typedef __attribute__((ext_vector_type(8))) short short8;
typedef __attribute__((ext_vector_type(4))) float floatx4;
typedef __attribute__((ext_vector_type(2))) float floatx2;
typedef __attribute__((ext_vector_type(4))) unsigned short ushort4_t;
typedef unsigned short ushort_t;

__device__ __forceinline__ float sigmoidf_(float v) {
    return 1.0f / (1.0f + expf(-v));
}

// Fragment-packed layout for GEMM operands (Z and W):
//   chunk(tile t, half w, k0, ks, f) = 512 bf16 (1 KiB) in exact MFMA lane
//   order: element lane*8+kb holds Op[t*128+w*64+f*16+(lane&15)]
//                                   [k0*64+ks*32+(lane>>4)*8+kb]
__device__ __forceinline__ int pk_off(int t, int w, int k0, int ks, int f,
                                      int lane8, int kb) {
    return ((((t * 2 + w) * 16 + k0) * 2 + ks) * 4 + f) * 512 + lane8 * 8 + kb;
}

// async global->LDS, 16 B per lane (dest must be linear: base + lane*16)
__device__ __forceinline__ void gload16(const void* g, void* l) {
    __builtin_amdgcn_global_load_lds(
        (const __attribute__((address_space(1))) void*)g,
        (__attribute__((address_space(3))) void*)l, 16, 0, 0);
}

// ---------------------------------------------------------------------------
// K1: per-subchunk partial sums, ONE direction per block.
// grid 2048 = chunk(4b)|ct(3b)|b(3b)|dir(1b); launch_bounds(256,8) caps
// VGPR at 64 -> 8 waves/SIMD resident (was 4) to hide HBM latency.
// ---------------------------------------------------------------------------
__global__ __launch_bounds__(256, 8) void k_partials5(
    const float* __restrict__ x, const float* __restrict__ al,
    const float* __restrict__ dl, const float* __restrict__ bl,
    float* __restrict__ P)
{
    int bid   = blockIdx.x;
    int chunk = bid & 15;
    int ct    = (bid >> 4) & 7;
    int b     = (bid >> 7) & 7;
    int dir   = bid >> 10;
    int lane  = threadIdx.x & 63;
    int wave  = threadIdx.x >> 6;
    int c     = ct * 64 + lane;
    int sub   = chunk * 4 + wave;     // fwd subchunk 0..63
    int t0f   = sub * 64;
    int t0b   = (63 - sub) * 64;      // bwd subchunk start (reversed time)

    float aa[4], dd[4], bb[4];
    { float4 v = ((const float4*)al)[c]; aa[0]=v.x; aa[1]=v.y; aa[2]=v.z; aa[3]=v.w; }
    { float4 v = ((const float4*)dl)[c]; dd[0]=v.x; dd[1]=v.y; dd[2]=v.z; dd[3]=v.w; }
    { float4 v = ((const float4*)bl)[c]; bb[0]=v.x; bb[1]=v.y; bb[2]=v.z; bb[3]=v.w; }

    float A[H_], ri[H_], Lh[H_];
    #pragma unroll
    for (int h = 0; h < H_; ++h) {
        float alpha = sigmoidf_(aa[h]);
        float delta = sigmoidf_(dd[h]);
        float beta  = sigmoidf_(bb[h]);
        A[h] = alpha * beta;
        float r = fminf(fmaxf(1.0f - alpha * delta, EPS_), 1.0f - EPS_);
        Lh[h] = logf(r);
        ri[h] = 1.0f / r;
    }
    floatx2 ri2[2]  = {{ri[0], ri[1]}, {ri[2], ri[3]}};
    floatx2 AEP2[2] = {{A[0] * E60P, A[1] * E60P}, {A[2] * E60P, A[3] * E60P}};

    const float* xp = x + ((size_t)b * N_ + t0f) * C_ + c;

    int   t0   = dir ? t0b : t0f;
    floatx2 Ae2[2], T2[2];
    #pragma unroll
    for (int p = 0; p < 2; ++p) {
        Ae2[p] = (floatx2){A[2*p]   * expf(fminf(-Lh[2*p]   * (float)t0, 60.0f)),
                           A[2*p+1] * expf(fminf(-Lh[2*p+1] * (float)t0, 60.0f))};
        T2[p]  = (floatx2){0.f, 0.f};
    }

    if (dir == 0) {
        float cur[8];
        #pragma unroll
        for (int j = 0; j < 8; ++j) cur[j] = xp[(size_t)j * C_];
        #pragma unroll 1
        for (int g = 0; g < 8; ++g) {
            float nxt[8];
            if (g < 7) {
                #pragma unroll
                for (int j = 0; j < 8; ++j)
                    nxt[j] = xp[(size_t)(g * 8 + 8 + j) * C_];
            }
            #pragma unroll
            for (int j = 0; j < 8; ++j) {
                floatx2 xv2 = {cur[j], cur[j]};
                #pragma unroll
                for (int p = 0; p < 2; ++p) {
                    T2[p] += Ae2[p] * xv2;
                    Ae2[p] = __builtin_elementwise_min(Ae2[p] * ri2[p], AEP2[p]);
                }
            }
            if (g < 7) {
                #pragma unroll
                for (int j = 0; j < 8; ++j) cur[j] = nxt[j];
            }
        }
        float* pp = P + ((size_t)b * 64 + sub) * (H_ * C_) + c;
        pp[0]      = T2[0].x;  pp[C_]     = T2[0].y;
        pp[2 * C_] = T2[1].x;  pp[3 * C_] = T2[1].y;
    } else {
        float cur[8];
        #pragma unroll
        for (int j = 0; j < 8; ++j) cur[j] = xp[(size_t)(63 - j) * C_];
        #pragma unroll 1
        for (int g = 0; g < 8; ++g) {
            float nxt[8];
            if (g < 7) {
                #pragma unroll
                for (int j = 0; j < 8; ++j)
                    nxt[j] = xp[(size_t)(63 - (g * 8 + 8 + j)) * C_];
            }
            #pragma unroll
            for (int j = 0; j < 8; ++j) {
                floatx2 xv2 = {cur[j], cur[j]};
                #pragma unroll
                for (int p = 0; p < 2; ++p) {
                    T2[p] += Ae2[p] * xv2;
                    Ae2[p] = __builtin_elementwise_min(Ae2[p] * ri2[p], AEP2[p]);
                }
            }
            if (g < 7) {
                #pragma unroll
                for (int j = 0; j < 8; ++j) cur[j] = nxt[j];
            }
        }
        float* pp = P + ((size_t)(8 + b) * 64 + (63 - sub)) * (H_ * C_) + c;
        pp[0]      = T2[0].x;  pp[C_]     = T2[0].y;
        pp[2 * C_] = T2[1].x;  pp[3 * C_] = T2[1].y;
    }
}

// ---------------------------------------------------------------------------
// K2: exclusive scan over the 64 subchunks, per (dir,b,c,h).
// Register-resident: 64 independent loads in flight.
// ---------------------------------------------------------------------------
__global__ __launch_bounds__(256) void k_scan(float* __restrict__ P)
{
    int bid = blockIdx.x;
    int ct  = bid & 7;
    int b   = (bid >> 3) & 7;
    int dir = bid >> 6;
    int cl  = threadIdx.x & 63;
    int h   = threadIdx.x >> 6;
    int c   = ct * 64 + cl;

    float* base = P + ((size_t)(dir * 8 + b) * 64) * (H_ * C_) + h * C_ + c;

    float v[64];
    #pragma unroll
    for (int s = 0; s < 64; ++s) v[s] = base[s * (H_ * C_)];

    float run = 0.0f;
    #pragma unroll
    for (int s = 0; s < 64; ++s) { float t = v[s]; v[s] = run; run += t; }

    #pragma unroll
    for (int s = 0; s < 64; ++s) base[s * (H_ * C_)] = v[s];
}

// ---------------------------------------------------------------------------
// K3: apply, ONE direction per block. grid 2048 = chunk|ct|b|dir;
// launch_bounds(256,8) -> 8 waves/SIMD. Folded Ae = A*ep state; 8-deep
// prefetch; writes z in fragment-packed bf16 order.
// ---------------------------------------------------------------------------
__global__ __launch_bounds__(256, 8) void k_apply5(
    const float* __restrict__ x, const float* __restrict__ al,
    const float* __restrict__ dl, const float* __restrict__ bl,
    const float* __restrict__ eta, const float* __restrict__ P,
    ushort_t* __restrict__ Zp)
{
    int bid   = blockIdx.x;
    int chunk = bid & 15;
    int ct    = (bid >> 4) & 7;
    int b     = (bid >> 7) & 7;
    int dir   = bid >> 10;
    int lane  = threadIdx.x & 63;
    int wave  = threadIdx.x >> 6;
    int c     = ct * 64 + lane;
    int sub   = chunk * 4 + wave;
    int t0f   = sub * 64;
    int t0b   = (63 - sub) * 64;

    int ksv = lane >> 5, qv = (lane >> 3) & 3, kbv = lane & 7;
    int mt  = b * 32 + (t0f >> 7);
    int wq  = (t0f >> 6) & 1;

    float aa[4], dd[4], bb[4], ee[4];
    { float4 v = ((const float4*)al )[c]; aa[0]=v.x; aa[1]=v.y; aa[2]=v.z; aa[3]=v.w; }
    { float4 v = ((const float4*)dl )[c]; dd[0]=v.x; dd[1]=v.y; dd[2]=v.z; dd[3]=v.w; }
    { float4 v = ((const float4*)bl )[c]; bb[0]=v.x; bb[1]=v.y; bb[2]=v.z; bb[3]=v.w; }
    { float4 v = ((const float4*)eta)[c]; ee[0]=v.x; ee[1]=v.y; ee[2]=v.z; ee[3]=v.w; }

    float A[H_], rr[H_], ri[H_], Lh[H_];
    #pragma unroll
    for (int h = 0; h < H_; ++h) {
        float alpha = sigmoidf_(aa[h]);
        float delta = sigmoidf_(dd[h]);
        float beta  = sigmoidf_(bb[h]);
        A[h] = alpha * beta;
        float r = fminf(fmaxf(1.0f - alpha * delta, EPS_), 1.0f - EPS_);
        Lh[h] = logf(r);
        rr[h] = r;
        ri[h] = 1.0f / r;
    }
    const floatx2 E2M = {E60M, E60M};
    floatx2 ri2[2]  = {{ri[0], ri[1]}, {ri[2], ri[3]}};
    floatx2 rr2[2]  = {{rr[0], rr[1]}, {rr[2], rr[3]}};
    floatx2 ee2[2]  = {{ee[0], ee[1]}, {ee[2], ee[3]}};
    floatx2 AEP2[2] = {{A[0] * E60P, A[1] * E60P}, {A[2] * E60P, A[3] * E60P}};

    const float* xp = x + ((size_t)b * N_ + t0f) * C_ + c;

    if (dir == 0) {
        int offcF = pk_off(mt, wq, ct, ksv, 0, qv * 16, kbv);
        const float* cp = P + ((size_t)b * 64 + sub) * (H_ * C_) + c;
        floatx2 Ae2[2], em2[2], S2[2];
        #pragma unroll
        for (int p = 0; p < 2; ++p) {
            Ae2[p] = (floatx2){A[2*p]   * expf(fminf(-Lh[2*p]   * (float)t0f, 60.0f)),
                               A[2*p+1] * expf(fminf(-Lh[2*p+1] * (float)t0f, 60.0f))};
            em2[p] = (floatx2){expf(fmaxf( Lh[2*p]   * (float)t0f, -60.0f)),
                               expf(fmaxf( Lh[2*p+1] * (float)t0f, -60.0f))};
            S2[p]  = (floatx2){cp[(2*p) * C_], cp[(2*p+1) * C_]};
        }
        float cur[8];
        #pragma unroll
        for (int j = 0; j < 8; ++j) cur[j] = xp[(size_t)j * C_];
        #pragma unroll 1
        for (int g = 0; g < 8; ++g) {
            float nxt[8];
            if (g < 7) {
                #pragma unroll
                for (int j = 0; j < 8; ++j)
                    nxt[j] = xp[(size_t)(g * 8 + 8 + j) * C_];
            }
            #pragma unroll
            for (int j = 0; j < 8; ++j) {
                int i = g * 8 + j;
                floatx2 xv2 = {cur[j], cur[j]};
                floatx2 acc = {0.f, 0.f};
                #pragma unroll
                for (int p = 0; p < 2; ++p) {
                    S2[p] += Ae2[p] * xv2;
                    Ae2[p] = __builtin_elementwise_min(Ae2[p] * ri2[p], AEP2[p]);
                    acc   += ee2[p] * (em2[p] * S2[p]);
                    em2[p] = __builtin_elementwise_max(em2[p] * rr2[p], E2M);
                }
                float y = acc.x + acc.y;
                __hip_bfloat16 yb = __float2bfloat16(y);
                Zp[offcF + (i >> 4) * 512 + (i & 15) * 8] = *(ushort_t*)&yb;
            }
            if (g < 7) {
                #pragma unroll
                for (int j = 0; j < 8; ++j) cur[j] = nxt[j];
            }
        }
    } else {
        int offcB = pk_off(mt, wq, 8 + ct, ksv, 0, qv * 16, kbv);
        const float* cp = P + ((size_t)(8 + b) * 64 + (63 - sub)) * (H_ * C_) + c;
        floatx2 Ae2[2], em2[2], S2[2];
        #pragma unroll
        for (int p = 0; p < 2; ++p) {
            Ae2[p] = (floatx2){A[2*p]   * expf(fminf(-Lh[2*p]   * (float)t0b, 60.0f)),
                               A[2*p+1] * expf(fminf(-Lh[2*p+1] * (float)t0b, 60.0f))};
            em2[p] = (floatx2){expf(fmaxf( Lh[2*p]   * (float)t0b, -60.0f)),
                               expf(fmaxf( Lh[2*p+1] * (float)t0b, -60.0f))};
            S2[p]  = (floatx2){cp[(2*p) * C_], cp[(2*p+1) * C_]};
        }
        float cur[8];
        #pragma unroll
        for (int j = 0; j < 8; ++j) cur[j] = xp[(size_t)(63 - j) * C_];
        #pragma unroll 1
        for (int g = 0; g < 8; ++g) {
            float nxt[8];
            if (g < 7) {
                #pragma unroll
                for (int j = 0; j < 8; ++j)
                    nxt[j] = xp[(size_t)(63 - (g * 8 + 8 + j)) * C_];
            }
            #pragma unroll
            for (int j = 0; j < 8; ++j) {
                int i = 63 - (g * 8 + j);
                floatx2 xv2 = {cur[j], cur[j]};
                floatx2 acc = {0.f, 0.f};
                #pragma unroll
                for (int p = 0; p < 2; ++p) {
                    S2[p] += Ae2[p] * xv2;
                    Ae2[p] = __builtin_elementwise_min(Ae2[p] * ri2[p], AEP2[p]);
                    acc   += ee2[p] * (em2[p] * S2[p]);
                    em2[p] = __builtin_elementwise_max(em2[p] * rr2[p], E2M);
                }
                float y = acc.x + acc.y;
                __hip_bfloat16 yb = __float2bfloat16(y);
                Zp[offcB + (i >> 4) * 512 + (i & 15) * 8] = *(ushort_t*)&yb;
            }
            if (g < 7) {
                #pragma unroll
                for (int j = 0; j < 8; ++j) cur[j] = nxt[j];
            }
        }
    }
}

// ---------------------------------------------------------------------------
// cvt + permute proj_w fp32 -> fragment-packed bf16, 4 elems/thread
// ---------------------------------------------------------------------------
__global__ __launch_bounds__(256) void k_cvtw2(const float* __restrict__ w,
                                               ushort_t* __restrict__ Wp)
{
    int i4 = blockIdx.x * 256 + threadIdx.x;   // 131072 total
    int i  = i4 << 2;
    int n = i >> 10, k = i & 1023;
    int nt = n >> 7, rn = n & 127;
    int k0 = k >> 6, kk = k & 63;
    int off = pk_off(nt, rn >> 6, k0, kk >> 5, (rn >> 4) & 3,
                     ((kk >> 3) & 3) * 16 + (rn & 15), kk & 7);
    float4 v = ((const float4*)w)[i4];
    ushort4_t r;
    { __hip_bfloat16 t = __float2bfloat16(v.x); r.x = *(ushort_t*)&t; }
    { __hip_bfloat16 t = __float2bfloat16(v.y); r.y = *(ushort_t*)&t; }
    { __hip_bfloat16 t = __float2bfloat16(v.z); r.z = *(ushort_t*)&t; }
    { __hip_bfloat16 t = __float2bfloat16(v.w); r.w = *(ushort_t*)&t; }
    *(ushort4_t*)&Wp[off] = r;
}

// ---------------------------------------------------------------------------
// K4: GEMM out[32768,512] = Z @ W^T + bias, operands fragment-packed,
// m97 structure (round-1 version: 52 us, best measured).
// XCD swizzle: bid&7 = XCD = mt&7.
// ---------------------------------------------------------------------------
__global__ __launch_bounds__(256, 4) void k_gemm3(
    const ushort_t* __restrict__ Zp, const ushort_t* __restrict__ Wp,
    const float* __restrict__ bias, float* __restrict__ out)
{
    __shared__ __align__(16) char lds[32768];
    char*  ldsA = lds;            // [w][ks*4+f][512 bf16] linear
    char*  ldsB = lds + 16384;
    float* stg  = (float*)lds;

    int tid  = threadIdx.x;
    int lane = tid & 63, wave = tid >> 6;
    int wm   = wave & 1, wn = wave >> 1;
    int fr   = lane & 15, quad = lane >> 4;

    int bid = blockIdx.x;
    int mt  = ((bid >> 5) << 3) | (bid & 7);   // mt & 7 == bid & 7 == XCD
    int nt  = (bid >> 3) & 3;
    int m0  = mt * 128, n0 = nt * 128;

    const ushort_t* Az = Zp + ((size_t)(mt * 2) * 16) * 4096;  // w-half stride 65536
    const ushort_t* Bz = Wp + ((size_t)(nt * 2) * 16) * 4096;

    floatx4 acc[4][4];
    #pragma unroll
    for (int mf = 0; mf < 4; ++mf)
        #pragma unroll
        for (int nf = 0; nf < 4; ++nf)
            acc[mf][nf] = (floatx4){0.f, 0.f, 0.f, 0.f};

    for (int k0 = 0; k0 < 16; ++k0) {
        const ushort_t* As = Az + (size_t)k0 * 4096;
        const ushort_t* Bs = Bz + (size_t)k0 * 4096;
        // stage 32 KB: 8 x global_load_lds_dwordx4 per thread
        #pragma unroll
        for (int w = 0; w < 2; ++w)
            #pragma unroll
            for (int inst = 0; inst < 2; ++inst) {
                gload16(As + w * 65536 + inst * 2048 + tid * 8,
                        ldsA + w * 8192 + inst * 4096 + tid * 16);
                gload16(Bs + w * 65536 + inst * 2048 + tid * 8,
                        ldsB + w * 8192 + inst * 4096 + tid * 16);
            }
        asm volatile("s_waitcnt vmcnt(0)" ::: "memory");
        __syncthreads();

        #pragma unroll
        for (int ks = 0; ks < 2; ++ks) {
            short8 af[4], bf[4];
            #pragma unroll
            for (int f = 0; f < 4; ++f) {
                af[f] = *(const short8*)(ldsA + wm * 8192 + (ks * 4 + f) * 1024 + lane * 16);
                bf[f] = *(const short8*)(ldsB + wn * 8192 + (ks * 4 + f) * 1024 + lane * 16);
            }
            #pragma unroll
            for (int mf = 0; mf < 4; ++mf)
                #pragma unroll
                for (int nf = 0; nf < 4; ++nf)
                    acc[mf][nf] = __builtin_amdgcn_mfma_f32_16x16x32_bf16(
                        af[mf], bf[nf], acc[mf][nf], 0, 0, 0);
        }
        __syncthreads();
    }

    // ---- LDS-staged epilogue: 4 chunks of 32 rows, coalesced 512 B rows
    int rrow = tid >> 3;                 // 0..31
    int seg  = tid & 7;                  // 0..7
    int gcol = n0 + seg * 16;

    #pragma unroll
    for (int ch = 0; ch < 4; ++ch) {
        if ((wave & 1) == (ch >> 1)) {
            int ml = (ch & 1) * 2;
            #pragma unroll
            for (int mi = 0; mi < 2; ++mi) {
                #pragma unroll
                for (int nf = 0; nf < 4; ++nf) {
                    int col = wn * 64 + nf * 16 + fr;
                    #pragma unroll
                    for (int rg = 0; rg < 4; ++rg) {
                        int row = mi * 16 + quad * 4 + rg;
                        stg[row * 132 + col] = acc[ml + mi][nf][rg];
                    }
                }
            }
        }
        __syncthreads();
        {
            int gm = m0 + ch * 32 + rrow;
            const float* s = &stg[rrow * 132 + seg * 16];
            #pragma unroll
            for (int k = 0; k < 4; ++k) {
                float4 v  = *(const float4*)&s[k * 4];
                float4 bv = *(const float4*)&bias[gcol + k * 4];
                v.x += bv.x; v.y += bv.y; v.z += bv.z; v.w += bv.w;
                *(float4*)&out[(size_t)gm * 512 + gcol + k * 4] = v;
            }
        }
        __syncthreads();
    }
}

// ---------------------------------------------------------------------------
extern "C" void kernel_launch(void* const* d_in, const int* in_sizes, int n_in,
                              void* d_out, int out_size, void* d_ws, size_t ws_size,
                              hipStream_t stream)
{
    const float* x  = (const float*)d_in[0];
    const float* al = (const float*)d_in[1];
    const float* dl = (const float*)d_in[2];
    const float* bl = (const float*)d_in[3];
    const float* et = (const float*)d_in[4];
    const float* pw = (const float*)d_in[5];
    const float* pb = (const float*)d_in[6];
    float* out = (float*)d_out;

    // workspace:
    //   Zp bf16 packed [32768,1024] : 67,108,864 B
    //   P  f32  [2,B,64,H,C]        :  8,388,608 B
    //   Wp bf16 packed [512,1024]   :  1,048,576 B
    ushort_t* Zp = (ushort_t*)d_ws;
    float*    P  = (float*)((char*)d_ws + 67108864);
    ushort_t* Wp = (ushort_t*)((char*)d_ws + 75497472);

    hipLaunchKernelGGL(k_cvtw2,     dim3(512),  dim3(256), 0, stream, pw, Wp);
    hipLaunchKernelGGL(k_partials5, dim3(2048), dim3(256), 0, stream, x, al, dl, bl, P);
    hipLaunchKernelGGL(k_scan,      dim3(128),  dim3(256), 0, stream, P);
    hipLaunchKernelGGL(k_apply5,    dim3(2048), dim3(256), 0, stream, x, al, dl, bl, et, P, Zp);
    hipLaunchKernelGGL(k_gemm3,     dim3(1024), dim3(256), 0, stream, Zp, Wp, pb, out);
}

// Round 5
// 220.475 us; speedup vs baseline: 1.0210x; 1.0004x over previous
//
#include <hip/hip_runtime.h>
#include <hip/hip_bf16.h>

#define B_ 8
#define N_ 4096
#define C_ 512
#define H_ 4
#define EPS_ 1e-4f
#define E60P 1.14200739e26f   // expf(60)
#define E60M 8.7565108e-27f   // expf(-60)

typedef __attribute__((ext_vector_type(8))) short short8;
typedef __attribute__((ext_vector_type(4))) float floatx4;
typedef __attribute__((ext_vector_type(2))) float floatx2;
typedef __attribute__((ext_vector_type(4))) unsigned short ushort4_t;
typedef unsigned short ushort_t;

__device__ __forceinline__ float sigmoidf_(float v) {
    return 1.0f / (1.0f + expf(-v));
}

// Fragment-packed layout for GEMM operands (Z and W):
//   chunk(tile t, half w, k0, ks, f) = 512 bf16 (1 KiB) in exact MFMA lane
//   order: element lane*8+kb holds Op[t*128+w*64+f*16+(lane&15)]
//                                   [k0*64+ks*32+(lane>>4)*8+kb]
__device__ __forceinline__ int pk_off(int t, int w, int k0, int ks, int f,
                                      int lane8, int kb) {
    return ((((t * 2 + w) * 16 + k0) * 2 + ks) * 4 + f) * 512 + lane8 * 8 + kb;
}

// async global->LDS, 16 B per lane (dest must be linear: base + lane*16)
__device__ __forceinline__ void gload16(const void* g, void* l) {
    __builtin_amdgcn_global_load_lds(
        (const __attribute__((address_space(1))) void*)g,
        (__attribute__((address_space(3))) void*)l, 16, 0, 0);
}

// ---------------------------------------------------------------------------
// K1: per-subchunk partial sums, ONE direction per block.
// grid 2048 = chunk(4b)|ct(3b)|b(3b)|dir(1b); launch_bounds(256,8) caps
// VGPR at 64 -> 8 waves/SIMD resident to hide HBM latency.
// ---------------------------------------------------------------------------
__global__ __launch_bounds__(256, 8) void k_partials5(
    const float* __restrict__ x, const float* __restrict__ al,
    const float* __restrict__ dl, const float* __restrict__ bl,
    float* __restrict__ P)
{
    int bid   = blockIdx.x;
    int chunk = bid & 15;
    int ct    = (bid >> 4) & 7;
    int b     = (bid >> 7) & 7;
    int dir   = bid >> 10;
    int lane  = threadIdx.x & 63;
    int wave  = threadIdx.x >> 6;
    int c     = ct * 64 + lane;
    int sub   = chunk * 4 + wave;     // fwd subchunk 0..63
    int t0f   = sub * 64;
    int t0b   = (63 - sub) * 64;      // bwd subchunk start (reversed time)

    float aa[4], dd[4], bb[4];
    { float4 v = ((const float4*)al)[c]; aa[0]=v.x; aa[1]=v.y; aa[2]=v.z; aa[3]=v.w; }
    { float4 v = ((const float4*)dl)[c]; dd[0]=v.x; dd[1]=v.y; dd[2]=v.z; dd[3]=v.w; }
    { float4 v = ((const float4*)bl)[c]; bb[0]=v.x; bb[1]=v.y; bb[2]=v.z; bb[3]=v.w; }

    float A[H_], ri[H_], Lh[H_];
    #pragma unroll
    for (int h = 0; h < H_; ++h) {
        float alpha = sigmoidf_(aa[h]);
        float delta = sigmoidf_(dd[h]);
        float beta  = sigmoidf_(bb[h]);
        A[h] = alpha * beta;
        float r = fminf(fmaxf(1.0f - alpha * delta, EPS_), 1.0f - EPS_);
        Lh[h] = logf(r);
        ri[h] = 1.0f / r;
    }
    floatx2 ri2[2]  = {{ri[0], ri[1]}, {ri[2], ri[3]}};
    floatx2 AEP2[2] = {{A[0] * E60P, A[1] * E60P}, {A[2] * E60P, A[3] * E60P}};

    const float* xp = x + ((size_t)b * N_ + t0f) * C_ + c;

    int   t0   = dir ? t0b : t0f;
    floatx2 Ae2[2], T2[2];
    #pragma unroll
    for (int p = 0; p < 2; ++p) {
        Ae2[p] = (floatx2){A[2*p]   * expf(fminf(-Lh[2*p]   * (float)t0, 60.0f)),
                           A[2*p+1] * expf(fminf(-Lh[2*p+1] * (float)t0, 60.0f))};
        T2[p]  = (floatx2){0.f, 0.f};
    }

    if (dir == 0) {
        float cur[8];
        #pragma unroll
        for (int j = 0; j < 8; ++j) cur[j] = xp[(size_t)j * C_];
        #pragma unroll 1
        for (int g = 0; g < 8; ++g) {
            float nxt[8];
            if (g < 7) {
                #pragma unroll
                for (int j = 0; j < 8; ++j)
                    nxt[j] = xp[(size_t)(g * 8 + 8 + j) * C_];
            }
            #pragma unroll
            for (int j = 0; j < 8; ++j) {
                floatx2 xv2 = {cur[j], cur[j]};
                #pragma unroll
                for (int p = 0; p < 2; ++p) {
                    T2[p] += Ae2[p] * xv2;
                    Ae2[p] = __builtin_elementwise_min(Ae2[p] * ri2[p], AEP2[p]);
                }
            }
            if (g < 7) {
                #pragma unroll
                for (int j = 0; j < 8; ++j) cur[j] = nxt[j];
            }
        }
        float* pp = P + ((size_t)b * 64 + sub) * (H_ * C_) + c;
        pp[0]      = T2[0].x;  pp[C_]     = T2[0].y;
        pp[2 * C_] = T2[1].x;  pp[3 * C_] = T2[1].y;
    } else {
        float cur[8];
        #pragma unroll
        for (int j = 0; j < 8; ++j) cur[j] = xp[(size_t)(63 - j) * C_];
        #pragma unroll 1
        for (int g = 0; g < 8; ++g) {
            float nxt[8];
            if (g < 7) {
                #pragma unroll
                for (int j = 0; j < 8; ++j)
                    nxt[j] = xp[(size_t)(63 - (g * 8 + 8 + j)) * C_];
            }
            #pragma unroll
            for (int j = 0; j < 8; ++j) {
                floatx2 xv2 = {cur[j], cur[j]};
                #pragma unroll
                for (int p = 0; p < 2; ++p) {
                    T2[p] += Ae2[p] * xv2;
                    Ae2[p] = __builtin_elementwise_min(Ae2[p] * ri2[p], AEP2[p]);
                }
            }
            if (g < 7) {
                #pragma unroll
                for (int j = 0; j < 8; ++j) cur[j] = nxt[j];
            }
        }
        float* pp = P + ((size_t)(8 + b) * 64 + (63 - sub)) * (H_ * C_) + c;
        pp[0]      = T2[0].x;  pp[C_]     = T2[0].y;
        pp[2 * C_] = T2[1].x;  pp[3 * C_] = T2[1].y;
    }
}

// ---------------------------------------------------------------------------
// K2: exclusive scan over the 64 subchunks, per (dir,b,c,h).
// Register-resident: 64 independent loads in flight.
// ---------------------------------------------------------------------------
__global__ __launch_bounds__(256) void k_scan(float* __restrict__ P)
{
    int bid = blockIdx.x;
    int ct  = bid & 7;
    int b   = (bid >> 3) & 7;
    int dir = bid >> 6;
    int cl  = threadIdx.x & 63;
    int h   = threadIdx.x >> 6;
    int c   = ct * 64 + cl;

    float* base = P + ((size_t)(dir * 8 + b) * 64) * (H_ * C_) + h * C_ + c;

    float v[64];
    #pragma unroll
    for (int s = 0; s < 64; ++s) v[s] = base[s * (H_ * C_)];

    float run = 0.0f;
    #pragma unroll
    for (int s = 0; s < 64; ++s) { float t = v[s]; v[s] = run; run += t; }

    #pragma unroll
    for (int s = 0; s < 64; ++s) base[s * (H_ * C_)] = v[s];
}

// ---------------------------------------------------------------------------
// K3: apply, ONE direction per block, LDS-staged output tile.
// A wave's 64 steps x 64 lanes exactly tile one packed 8 KB chunk
// (col = k0*64+lane, row = i). During the recurrence each step does ONE
// 2 B ds_write (XOR-swizzled, conflict-free) instead of a scattered 2 B
// global store; after __syncthreads each lane emits 8 coalesced 16 B
// global stores (1 KB per wave-instruction). VMEM stores/thread: 64 -> 8.
// ---------------------------------------------------------------------------
__global__ __launch_bounds__(256, 5) void k_apply6(
    const float* __restrict__ x, const float* __restrict__ al,
    const float* __restrict__ dl, const float* __restrict__ bl,
    const float* __restrict__ eta, const float* __restrict__ P,
    ushort_t* __restrict__ Zp)
{
    __shared__ __align__(16) ushort_t zlds[4][4096];   // 8 KB per wave

    int bid   = blockIdx.x;
    int chunk = bid & 15;
    int ct    = (bid >> 4) & 7;
    int b     = (bid >> 7) & 7;
    int dir   = bid >> 10;
    int lane  = threadIdx.x & 63;
    int wave  = threadIdx.x >> 6;
    int c     = ct * 64 + lane;
    int sub   = chunk * 4 + wave;
    int t0f   = sub * 64;
    int t0b   = (63 - sub) * 64;

    int mt  = b * 32 + (t0f >> 7);
    int wq  = (t0f >> 6) & 1;
    char* zw = (char*)&zlds[wave][0];

    float aa[4], dd[4], bb[4], ee[4];
    { float4 v = ((const float4*)al )[c]; aa[0]=v.x; aa[1]=v.y; aa[2]=v.z; aa[3]=v.w; }
    { float4 v = ((const float4*)dl )[c]; dd[0]=v.x; dd[1]=v.y; dd[2]=v.z; dd[3]=v.w; }
    { float4 v = ((const float4*)bl )[c]; bb[0]=v.x; bb[1]=v.y; bb[2]=v.z; bb[3]=v.w; }
    { float4 v = ((const float4*)eta)[c]; ee[0]=v.x; ee[1]=v.y; ee[2]=v.z; ee[3]=v.w; }

    float A[H_], rr[H_], ri[H_], Lh[H_];
    #pragma unroll
    for (int h = 0; h < H_; ++h) {
        float alpha = sigmoidf_(aa[h]);
        float delta = sigmoidf_(dd[h]);
        float beta  = sigmoidf_(bb[h]);
        A[h] = alpha * beta;
        float r = fminf(fmaxf(1.0f - alpha * delta, EPS_), 1.0f - EPS_);
        Lh[h] = logf(r);
        rr[h] = r;
        ri[h] = 1.0f / r;
    }
    const floatx2 E2M = {E60M, E60M};
    floatx2 ri2[2]  = {{ri[0], ri[1]}, {ri[2], ri[3]}};
    floatx2 rr2[2]  = {{rr[0], rr[1]}, {rr[2], rr[3]}};
    floatx2 ee2[2]  = {{ee[0], ee[1]}, {ee[2], ee[3]}};
    floatx2 AEP2[2] = {{A[0] * E60P, A[1] * E60P}, {A[2] * E60P, A[3] * E60P}};

    const float* xp = x + ((size_t)b * N_ + t0f) * C_ + c;

    if (dir == 0) {
        const float* cp = P + ((size_t)b * 64 + sub) * (H_ * C_) + c;
        floatx2 Ae2[2], em2[2], S2[2];
        #pragma unroll
        for (int p = 0; p < 2; ++p) {
            Ae2[p] = (floatx2){A[2*p]   * expf(fminf(-Lh[2*p]   * (float)t0f, 60.0f)),
                               A[2*p+1] * expf(fminf(-Lh[2*p+1] * (float)t0f, 60.0f))};
            em2[p] = (floatx2){expf(fmaxf( Lh[2*p]   * (float)t0f, -60.0f)),
                               expf(fmaxf( Lh[2*p+1] * (float)t0f, -60.0f))};
            S2[p]  = (floatx2){cp[(2*p) * C_], cp[(2*p+1) * C_]};
        }
        float cur[8];
        #pragma unroll
        for (int j = 0; j < 8; ++j) cur[j] = xp[(size_t)j * C_];
        #pragma unroll 1
        for (int g = 0; g < 8; ++g) {
            float nxt[8];
            if (g < 7) {
                #pragma unroll
                for (int j = 0; j < 8; ++j)
                    nxt[j] = xp[(size_t)(g * 8 + 8 + j) * C_];
            }
            #pragma unroll
            for (int j = 0; j < 8; ++j) {
                int i = g * 8 + j;
                floatx2 xv2 = {cur[j], cur[j]};
                floatx2 acc = {0.f, 0.f};
                #pragma unroll
                for (int p = 0; p < 2; ++p) {
                    S2[p] += Ae2[p] * xv2;
                    Ae2[p] = __builtin_elementwise_min(Ae2[p] * ri2[p], AEP2[p]);
                    acc   += ee2[p] * (em2[p] * S2[p]);
                    em2[p] = __builtin_elementwise_max(em2[p] * rr2[p], E2M);
                }
                float y = acc.x + acc.y;
                __hip_bfloat16 yb = __float2bfloat16(y);
                int bo = (i * 128 + lane * 2) ^ ((i & 7) << 4);
                *(ushort_t*)(zw + bo) = *(ushort_t*)&yb;
            }
            if (g < 7) {
                #pragma unroll
                for (int j = 0; j < 8; ++j) cur[j] = nxt[j];
            }
        }
    } else {
        const float* cp = P + ((size_t)(8 + b) * 64 + (63 - sub)) * (H_ * C_) + c;
        floatx2 Ae2[2], em2[2], S2[2];
        #pragma unroll
        for (int p = 0; p < 2; ++p) {
            Ae2[p] = (floatx2){A[2*p]   * expf(fminf(-Lh[2*p]   * (float)t0b, 60.0f)),
                               A[2*p+1] * expf(fminf(-Lh[2*p+1] * (float)t0b, 60.0f))};
            em2[p] = (floatx2){expf(fmaxf( Lh[2*p]   * (float)t0b, -60.0f)),
                               expf(fmaxf( Lh[2*p+1] * (float)t0b, -60.0f))};
            S2[p]  = (floatx2){cp[(2*p) * C_], cp[(2*p+1) * C_]};
        }
        float cur[8];
        #pragma unroll
        for (int j = 0; j < 8; ++j) cur[j] = xp[(size_t)(63 - j) * C_];
        #pragma unroll 1
        for (int g = 0; g < 8; ++g) {
            float nxt[8];
            if (g < 7) {
                #pragma unroll
                for (int j = 0; j < 8; ++j)
                    nxt[j] = xp[(size_t)(63 - (g * 8 + 8 + j)) * C_];
            }
            #pragma unroll
            for (int j = 0; j < 8; ++j) {
                int i = 63 - (g * 8 + j);
                floatx2 xv2 = {cur[j], cur[j]};
                floatx2 acc = {0.f, 0.f};
                #pragma unroll
                for (int p = 0; p < 2; ++p) {
                    S2[p] += Ae2[p] * xv2;
                    Ae2[p] = __builtin_elementwise_min(Ae2[p] * ri2[p], AEP2[p]);
                    acc   += ee2[p] * (em2[p] * S2[p]);
                    em2[p] = __builtin_elementwise_max(em2[p] * rr2[p], E2M);
                }
                float y = acc.x + acc.y;
                __hip_bfloat16 yb = __float2bfloat16(y);
                int bo = (i * 128 + lane * 2) ^ ((i & 7) << 4);
                *(ushort_t*)(zw + bo) = *(ushort_t*)&yb;
            }
            if (g < 7) {
                #pragma unroll
                for (int j = 0; j < 8; ++j) cur[j] = nxt[j];
            }
        }
    }

    __syncthreads();

    // ---- coalesced flush: wave's 8 KB chunk, 8 x 16 B per lane
    {
        int k0c = dir ? (8 + ct) : ct;
        size_t cb = ((size_t)((mt * 2 + wq) * 16 + k0c)) * 4096;   // elements
        #pragma unroll
        for (int ks = 0; ks < 2; ++ks)
            #pragma unroll
            for (int f = 0; f < 4; ++f) {
                int row = f * 16 + (lane & 15);
                int rb  = (row * 128 + ks * 64 + (lane >> 4) * 16) ^ ((row & 7) << 4);
                short8 v = *(const short8*)(zw + rb);
                *(short8*)(Zp + cb + (ks * 4 + f) * 512 + lane * 8) = v;
            }
    }
}

// ---------------------------------------------------------------------------
// cvt + permute proj_w fp32 -> fragment-packed bf16, 4 elems/thread
// ---------------------------------------------------------------------------
__global__ __launch_bounds__(256) void k_cvtw2(const float* __restrict__ w,
                                               ushort_t* __restrict__ Wp)
{
    int i4 = blockIdx.x * 256 + threadIdx.x;   // 131072 total
    int i  = i4 << 2;
    int n = i >> 10, k = i & 1023;
    int nt = n >> 7, rn = n & 127;
    int k0 = k >> 6, kk = k & 63;
    int off = pk_off(nt, rn >> 6, k0, kk >> 5, (rn >> 4) & 3,
                     ((kk >> 3) & 3) * 16 + (rn & 15), kk & 7);
    float4 v = ((const float4*)w)[i4];
    ushort4_t r;
    { __hip_bfloat16 t = __float2bfloat16(v.x); r.x = *(ushort_t*)&t; }
    { __hip_bfloat16 t = __float2bfloat16(v.y); r.y = *(ushort_t*)&t; }
    { __hip_bfloat16 t = __float2bfloat16(v.z); r.z = *(ushort_t*)&t; }
    { __hip_bfloat16 t = __float2bfloat16(v.w); r.w = *(ushort_t*)&t; }
    *(ushort4_t*)&Wp[off] = r;
}

// ---------------------------------------------------------------------------
// K4: GEMM out[32768,512] = Z @ W^T + bias, operands fragment-packed,
// m97 structure (round-1 version: 52 us, best measured).
// XCD swizzle: bid&7 = XCD = mt&7.
// ---------------------------------------------------------------------------
__global__ __launch_bounds__(256, 4) void k_gemm3(
    const ushort_t* __restrict__ Zp, const ushort_t* __restrict__ Wp,
    const float* __restrict__ bias, float* __restrict__ out)
{
    __shared__ __align__(16) char lds[32768];
    char*  ldsA = lds;            // [w][ks*4+f][512 bf16] linear
    char*  ldsB = lds + 16384;
    float* stg  = (float*)lds;

    int tid  = threadIdx.x;
    int lane = tid & 63, wave = tid >> 6;
    int wm   = wave & 1, wn = wave >> 1;
    int fr   = lane & 15, quad = lane >> 4;

    int bid = blockIdx.x;
    int mt  = ((bid >> 5) << 3) | (bid & 7);   // mt & 7 == bid & 7 == XCD
    int nt  = (bid >> 3) & 3;
    int m0  = mt * 128, n0 = nt * 128;

    const ushort_t* Az = Zp + ((size_t)(mt * 2) * 16) * 4096;  // w-half stride 65536
    const ushort_t* Bz = Wp + ((size_t)(nt * 2) * 16) * 4096;

    floatx4 acc[4][4];
    #pragma unroll
    for (int mf = 0; mf < 4; ++mf)
        #pragma unroll
        for (int nf = 0; nf < 4; ++nf)
            acc[mf][nf] = (floatx4){0.f, 0.f, 0.f, 0.f};

    for (int k0 = 0; k0 < 16; ++k0) {
        const ushort_t* As = Az + (size_t)k0 * 4096;
        const ushort_t* Bs = Bz + (size_t)k0 * 4096;
        // stage 32 KB: 8 x global_load_lds_dwordx4 per thread
        #pragma unroll
        for (int w = 0; w < 2; ++w)
            #pragma unroll
            for (int inst = 0; inst < 2; ++inst) {
                gload16(As + w * 65536 + inst * 2048 + tid * 8,
                        ldsA + w * 8192 + inst * 4096 + tid * 16);
                gload16(Bs + w * 65536 + inst * 2048 + tid * 8,
                        ldsB + w * 8192 + inst * 4096 + tid * 16);
            }
        asm volatile("s_waitcnt vmcnt(0)" ::: "memory");
        __syncthreads();

        #pragma unroll
        for (int ks = 0; ks < 2; ++ks) {
            short8 af[4], bf[4];
            #pragma unroll
            for (int f = 0; f < 4; ++f) {
                af[f] = *(const short8*)(ldsA + wm * 8192 + (ks * 4 + f) * 1024 + lane * 16);
                bf[f] = *(const short8*)(ldsB + wn * 8192 + (ks * 4 + f) * 1024 + lane * 16);
            }
            #pragma unroll
            for (int mf = 0; mf < 4; ++mf)
                #pragma unroll
                for (int nf = 0; nf < 4; ++nf)
                    acc[mf][nf] = __builtin_amdgcn_mfma_f32_16x16x32_bf16(
                        af[mf], bf[nf], acc[mf][nf], 0, 0, 0);
        }
        __syncthreads();
    }

    // ---- LDS-staged epilogue: 4 chunks of 32 rows, coalesced 512 B rows
    int rrow = tid >> 3;                 // 0..31
    int seg  = tid & 7;                  // 0..7
    int gcol = n0 + seg * 16;

    #pragma unroll
    for (int ch = 0; ch < 4; ++ch) {
        if ((wave & 1) == (ch >> 1)) {
            int ml = (ch & 1) * 2;
            #pragma unroll
            for (int mi = 0; mi < 2; ++mi) {
                #pragma unroll
                for (int nf = 0; nf < 4; ++nf) {
                    int col = wn * 64 + nf * 16 + fr;
                    #pragma unroll
                    for (int rg = 0; rg < 4; ++rg) {
                        int row = mi * 16 + quad * 4 + rg;
                        stg[row * 132 + col] = acc[ml + mi][nf][rg];
                    }
                }
            }
        }
        __syncthreads();
        {
            int gm = m0 + ch * 32 + rrow;
            const float* s = &stg[rrow * 132 + seg * 16];
            #pragma unroll
            for (int k = 0; k < 4; ++k) {
                float4 v  = *(const float4*)&s[k * 4];
                float4 bv = *(const float4*)&bias[gcol + k * 4];
                v.x += bv.x; v.y += bv.y; v.z += bv.z; v.w += bv.w;
                *(float4*)&out[(size_t)gm * 512 + gcol + k * 4] = v;
            }
        }
        __syncthreads();
    }
}

// ---------------------------------------------------------------------------
extern "C" void kernel_launch(void* const* d_in, const int* in_sizes, int n_in,
                              void* d_out, int out_size, void* d_ws, size_t ws_size,
                              hipStream_t stream)
{
    const float* x  = (const float*)d_in[0];
    const float* al = (const float*)d_in[1];
    const float* dl = (const float*)d_in[2];
    const float* bl = (const float*)d_in[3];
    const float* et = (const float*)d_in[4];
    const float* pw = (const float*)d_in[5];
    const float* pb = (const float*)d_in[6];
    float* out = (float*)d_out;

    // workspace:
    //   Zp bf16 packed [32768,1024] : 67,108,864 B
    //   P  f32  [2,B,64,H,C]        :  8,388,608 B
    //   Wp bf16 packed [512,1024]   :  1,048,576 B
    ushort_t* Zp = (ushort_t*)d_ws;
    float*    P  = (float*)((char*)d_ws + 67108864);
    ushort_t* Wp = (ushort_t*)((char*)d_ws + 75497472);

    hipLaunchKernelGGL(k_cvtw2,     dim3(512),  dim3(256), 0, stream, pw, Wp);
    hipLaunchKernelGGL(k_partials5, dim3(2048), dim3(256), 0, stream, x, al, dl, bl, P);
    hipLaunchKernelGGL(k_scan,      dim3(128),  dim3(256), 0, stream, P);
    hipLaunchKernelGGL(k_apply6,    dim3(2048), dim3(256), 0, stream, x, al, dl, bl, et, P, Zp);
    hipLaunchKernelGGL(k_gemm3,     dim3(1024), dim3(256), 0, stream, Zp, Wp, pb, out);
}